// Round 1
// baseline (734.548 us; speedup 1.0000x reference)
//
#include <hip/hip_runtime.h>
#include <hip/hip_bf16.h>
#include <math.h>

typedef unsigned short u16;
typedef unsigned int u32;
typedef __bf16 bf16x8 __attribute__((ext_vector_type(8)));
typedef float f32x4 __attribute__((ext_vector_type(4)));

#define T_TOK 4096
#define HID   1024
#define INTER 4096
#define NEXP  8

// ---------------- workspace layout (bytes) ----------------
// counts:   0        (32 B, memset 0)
// offs:     256      (32 B)
// tlist:    1024     (8*4096*4   = 131072)
// wlist:    132096   (8*4096*4   = 131072)
// x_bf16:   263168   (4096*1024*2 = 8388608)
// w1t:      8651776  (8*4096*1024*2 = 67108864)   [E][I][H] bf16
// w2t:      75760640 (8*1024*4096*2 = 67108864)   [E][H][I] bf16
// h1b:      142869504(8192*4096*2   = 67108864)   [pair][I] bf16
// total:    209978368
#define WS_NEEDED 209978368ull

__device__ __forceinline__ u16 f2bf(float f) {
    u32 u = __builtin_bit_cast(u32, f);
    u += 0x7FFFu + ((u >> 16) & 1u);   // round-to-nearest-even
    return (u16)(u >> 16);
}

__device__ __forceinline__ void gl2lds16(const void* g, void* l) {
    __builtin_amdgcn_global_load_lds(
        (const __attribute__((address_space(1))) u32*)g,
        (__attribute__((address_space(3))) u32*)l, 16, 0, 0);
}

// ---------------- router: fp32 logits + top-2 lists ----------------
__global__ __launch_bounds__(256) void router_kernel(
    const float* __restrict__ x, const float* __restrict__ gw,
    float* __restrict__ logits, int* __restrict__ counts,
    int* __restrict__ tlist, float* __restrict__ wlist)
{
    const int lane = threadIdx.x & 63, wv = threadIdx.x >> 6;
    const int t = blockIdx.x * 4 + wv;
    const float* xr = x + (size_t)t * HID;
    float a[8] = {0.f,0.f,0.f,0.f,0.f,0.f,0.f,0.f};
    for (int h = lane; h < HID; h += 64) {
        float xv = xr[h];
        const float4* g4 = (const float4*)(gw + h * 8);
        float4 g0 = g4[0], g1 = g4[1];
        a[0] += xv * g0.x; a[1] += xv * g0.y; a[2] += xv * g0.z; a[3] += xv * g0.w;
        a[4] += xv * g1.x; a[5] += xv * g1.y; a[6] += xv * g1.z; a[7] += xv * g1.w;
    }
#pragma unroll
    for (int e = 0; e < 8; e++) {
        float v = a[e];
        for (int o = 32; o > 0; o >>= 1) v += __shfl_down(v, o, 64);
        a[e] = v;
    }
    if (lane == 0) {
#pragma unroll
        for (int e = 0; e < 8; e++) logits[(size_t)t * 8 + e] = a[e];
        int e1 = 0; float b1 = a[0];
        for (int e = 1; e < 8; e++) if (a[e] > b1) { b1 = a[e]; e1 = e; }
        int e2 = -1; float b2 = -1e30f;
        for (int e = 0; e < 8; e++) if (e != e1 && a[e] > b2) { b2 = a[e]; e2 = e; }
        // softmax->top2->renorm == 2-way softmax over (b1,b2)
        float wa = 1.0f / (1.0f + expf(b2 - b1));
        float wb = 1.0f - wa;
        int p = atomicAdd(&counts[e1], 1);
        tlist[e1 * T_TOK + p] = t; wlist[e1 * T_TOK + p] = wa;
        p = atomicAdd(&counts[e2], 1);
        tlist[e2 * T_TOK + p] = t; wlist[e2 * T_TOK + p] = wb;
    }
}

__global__ void scan_kernel(const int* __restrict__ counts, int* __restrict__ offs)
{
    if (threadIdx.x == 0) {
        int s = 0;
        for (int e = 0; e < 8; e++) { offs[e] = s; s += counts[e]; }
    }
}

// ---------------- fp32 -> bf16 convert (x) ----------------
__global__ __launch_bounds__(256) void convert_x_kernel(
    const float* __restrict__ src, u16* __restrict__ dst)
{
    const int idx = (blockIdx.x * 256 + threadIdx.x) * 8;
    float4 f0 = *(const float4*)(src + idx);
    float4 f1 = *(const float4*)(src + idx + 4);
    uint4 o;
    o.x = (u32)f2bf(f0.x) | ((u32)f2bf(f0.y) << 16);
    o.y = (u32)f2bf(f0.z) | ((u32)f2bf(f0.w) << 16);
    o.z = (u32)f2bf(f1.x) | ((u32)f2bf(f1.y) << 16);
    o.w = (u32)f2bf(f1.z) | ((u32)f2bf(f1.w) << 16);
    *(uint4*)(dst + idx) = o;
}

// ---------------- transpose + convert: src[E][R][C] f32 -> dst[E][C][R] bf16 ----
__global__ __launch_bounds__(256) void transpose_convert_kernel(
    const float* __restrict__ src, u16* __restrict__ dst, int R, int C)
{
    __shared__ float tile[64][65];
    const int e = blockIdx.z;
    const int c0 = blockIdx.x * 64, r0 = blockIdx.y * 64;
    const float* s = src + (size_t)e * R * C;
#pragma unroll
    for (int j = 0; j < 16; j++) {
        int idx = j * 256 + threadIdx.x;
        int r = idx >> 6, c = idx & 63;
        tile[r][c] = s[(size_t)(r0 + r) * C + c0 + c];
    }
    __syncthreads();
    u16* d = dst + (size_t)e * C * R;
#pragma unroll
    for (int j = 0; j < 8; j++) {
        int idx = j * 256 + threadIdx.x;     // 2048 pairs
        int c = idx >> 5;
        int r = (idx & 31) * 2;
        u32 v = (u32)f2bf(tile[r][c]) | ((u32)f2bf(tile[r + 1][c]) << 16);
        *(u32*)(&d[(size_t)(c0 + c) * R + r0 + r]) = v;
    }
}

// ---------------- GEMM1: h1 = gelu(x_gathered @ w1), bf16 MFMA ----------------
__global__ __launch_bounds__(256, 1) void gemm1_kernel(
    const u16* __restrict__ xb, const u16* __restrict__ w1t,
    const int* __restrict__ counts, const int* __restrict__ offs,
    const int* __restrict__ tlist, u16* __restrict__ h1b)
{
    const int e = blockIdx.z, mt = blockIdx.y, nt = blockIdx.x;
    const int cnt = counts[e];
    if (mt * 128 >= cnt) return;
    __shared__ __align__(16) u16 As[8192];   // [m 0..127][k-chunk swizzled]
    __shared__ __align__(16) u16 Bs[8192];   // [n 0..127][k-chunk swizzled]
    __shared__ int toks[128];
    const int tid = threadIdx.x, lane = tid & 63, wv = tid >> 6;
    if (tid < 128) toks[tid] = tlist[e * T_TOK + min(mt * 128 + tid, cnt - 1)];
    __syncthreads();

    f32x4 acc[4][4] = {};
    const int wm = wv & 1, wn = wv >> 1;
    const int sj = tid >> 3, sp = tid & 7;

    // hoist staging bases (swizzle: chunk jj stored at pos (jj+row)&7)
    size_t abase[4], bbase[4];
    const u16* w1base = w1t + ((size_t)e * INTER + (size_t)nt * 128) * HID;
#pragma unroll
    for (int j = 0; j < 4; j++) {
        int m = j * 32 + sj;
        abase[j] = (size_t)toks[m] * HID + ((sp - m) & 7) * 8;
        bbase[j] = (size_t)m * HID + ((sp - m) & 7) * 8;   // n == m pattern
    }

    for (int h0 = 0; h0 < HID; h0 += 64) {
#pragma unroll
        for (int j = 0; j < 4; j++)
            gl2lds16(xb + abase[j] + h0, &As[j * 2048 + wv * 512]);
#pragma unroll
        for (int j = 0; j < 4; j++)
            gl2lds16(w1base + bbase[j] + h0, &Bs[j * 2048 + wv * 512]);
        __syncthreads();
#pragma unroll
        for (int kk = 0; kk < 2; kk++) {
            bf16x8 a[4], b[4];
            const int jjb = kk * 4 + (lane >> 4);
#pragma unroll
            for (int i = 0; i < 4; i++) {
                int m = wm * 64 + i * 16 + (lane & 15);
                a[i] = *(const bf16x8*)&As[m * 64 + ((jjb + m) & 7) * 8];
            }
#pragma unroll
            for (int i = 0; i < 4; i++) {
                int n = wn * 64 + i * 16 + (lane & 15);
                b[i] = *(const bf16x8*)&Bs[n * 64 + ((jjb + n) & 7) * 8];
            }
#pragma unroll
            for (int i = 0; i < 4; i++)
#pragma unroll
                for (int j = 0; j < 4; j++)
                    acc[i][j] = __builtin_amdgcn_mfma_f32_16x16x32_bf16(
                        a[i], b[j], acc[i][j], 0, 0, 0);
        }
        __syncthreads();
    }

    const int pb = offs[e] + mt * 128;
#pragma unroll
    for (int i = 0; i < 4; i++) {
        const int mb = wm * 64 + i * 16 + ((lane >> 4) << 2);
#pragma unroll
        for (int j = 0; j < 4; j++) {
            const int n = nt * 128 + wn * 64 + j * 16 + (lane & 15);
#pragma unroll
            for (int r = 0; r < 4; r++) {
                const int m = mb + r;
                if (mt * 128 + m < cnt) {
                    float v = acc[i][j][r];
                    v = 0.5f * v * (1.0f + erff(v * 0.70710678118654752f)); // exact gelu
                    h1b[(size_t)(pb + m) * INTER + n] = f2bf(v);
                }
            }
        }
    }
}

// ---------------- GEMM2: out += weight * (h1 @ w2), bf16 MFMA, atomic combine ----
__global__ __launch_bounds__(256, 1) void gemm2_kernel(
    const u16* __restrict__ h1b, const u16* __restrict__ w2t,
    const int* __restrict__ counts, const int* __restrict__ offs,
    const int* __restrict__ tlist, const float* __restrict__ wlist,
    float* __restrict__ out)
{
    const int e = blockIdx.z, mt = blockIdx.y, nt = blockIdx.x;
    const int cnt = counts[e];
    if (mt * 128 >= cnt) return;
    __shared__ __align__(16) u16 As[8192];
    __shared__ __align__(16) u16 Bs[8192];
    __shared__ int toks[128];
    __shared__ float wgt[128];
    const int tid = threadIdx.x, lane = tid & 63, wv = tid >> 6;
    if (tid < 128) {
        int gi = e * T_TOK + min(mt * 128 + tid, cnt - 1);
        toks[tid] = tlist[gi];
        wgt[tid] = wlist[gi];
    }
    __syncthreads();

    f32x4 acc[4][4] = {};
    const int wm = wv & 1, wn = wv >> 1;
    const int sj = tid >> 3, sp = tid & 7;

    size_t abase[4], bbase[4];
    const u16* w2base = w2t + ((size_t)e * HID + (size_t)nt * 128) * INTER;
    const int prow = offs[e];
#pragma unroll
    for (int j = 0; j < 4; j++) {
        int m = j * 32 + sj;
        int row = prow + min(mt * 128 + m, cnt - 1);
        abase[j] = (size_t)row * INTER + ((sp - m) & 7) * 8;
        bbase[j] = (size_t)m * INTER + ((sp - m) & 7) * 8;
    }

    for (int i0 = 0; i0 < INTER; i0 += 64) {
#pragma unroll
        for (int j = 0; j < 4; j++)
            gl2lds16(h1b + abase[j] + i0, &As[j * 2048 + wv * 512]);
#pragma unroll
        for (int j = 0; j < 4; j++)
            gl2lds16(w2base + bbase[j] + i0, &Bs[j * 2048 + wv * 512]);
        __syncthreads();
#pragma unroll
        for (int kk = 0; kk < 2; kk++) {
            bf16x8 a[4], b[4];
            const int jjb = kk * 4 + (lane >> 4);
#pragma unroll
            for (int i = 0; i < 4; i++) {
                int m = wm * 64 + i * 16 + (lane & 15);
                a[i] = *(const bf16x8*)&As[m * 64 + ((jjb + m) & 7) * 8];
            }
#pragma unroll
            for (int i = 0; i < 4; i++) {
                int n = wn * 64 + i * 16 + (lane & 15);
                b[i] = *(const bf16x8*)&Bs[n * 64 + ((jjb + n) & 7) * 8];
            }
#pragma unroll
            for (int i = 0; i < 4; i++)
#pragma unroll
                for (int j = 0; j < 4; j++)
                    acc[i][j] = __builtin_amdgcn_mfma_f32_16x16x32_bf16(
                        a[i], b[j], acc[i][j], 0, 0, 0);
        }
        __syncthreads();
    }

#pragma unroll
    for (int i = 0; i < 4; i++) {
        const int mb = wm * 64 + i * 16 + ((lane >> 4) << 2);
#pragma unroll
        for (int j = 0; j < 4; j++) {
            const int n = nt * 128 + wn * 64 + j * 16 + (lane & 15);
#pragma unroll
            for (int r = 0; r < 4; r++) {
                const int m = mb + r;
                if (mt * 128 + m < cnt) {
                    atomicAdd(&out[(size_t)toks[m] * HID + n], acc[i][j][r] * wgt[m]);
                }
            }
        }
    }
}

extern "C" void kernel_launch(void* const* d_in, const int* in_sizes, int n_in,
                              void* d_out, int out_size, void* d_ws, size_t ws_size,
                              hipStream_t stream)
{
    const float* x  = (const float*)d_in[0];   // [4,1024,1024]
    const float* gw = (const float*)d_in[1];   // [1024,8]
    const float* w1 = (const float*)d_in[2];   // [8,1024,4096]
    const float* w2 = (const float*)d_in[3];   // [8,4096,1024]
    float* out    = (float*)d_out;             // 4194304 out + 32768 logits
    float* logits = out + 4194304;

    char* ws = (char*)d_ws;
    int*   counts = (int*)ws;
    int*   offs   = (int*)(ws + 256);
    int*   tlist  = (int*)(ws + 1024);
    float* wlist  = (float*)(ws + 132096);
    u16*   xb     = (u16*)(ws + 263168);
    u16*   w1t    = (u16*)(ws + 8651776);
    u16*   w2t    = (u16*)(ws + 75760640);
    u16*   h1b    = (u16*)(ws + 142869504);

    if (ws_size < WS_NEEDED) return;  // clean failure mode if scratch too small

    hipMemsetAsync(out, 0, 4194304 * sizeof(float), stream);
    hipMemsetAsync(counts, 0, 256, stream);

    router_kernel<<<1024, 256, 0, stream>>>(x, gw, logits, counts, tlist, wlist);
    scan_kernel<<<1, 64, 0, stream>>>(counts, offs);
    convert_x_kernel<<<2048, 256, 0, stream>>>(x, xb);
    // w1 [E][H][I] -> w1t [E][I][H]
    transpose_convert_kernel<<<dim3(64, 16, 8), 256, 0, stream>>>(w1, w1t, HID, INTER);
    // w2 [E][I][H] -> w2t [E][H][I]
    transpose_convert_kernel<<<dim3(16, 64, 8), 256, 0, stream>>>(w2, w2t, INTER, HID);

    gemm1_kernel<<<dim3(32, 32, 8), 256, 0, stream>>>(xb, w1t, counts, offs, tlist, h1b);
    gemm2_kernel<<<dim3(8, 32, 8), 256, 0, stream>>>(h1b, w2t, counts, offs, tlist, wlist, out);
}

// Round 2
// 707.542 us; speedup vs baseline: 1.0382x; 1.0382x over previous
//
#include <hip/hip_runtime.h>
#include <hip/hip_bf16.h>
#include <math.h>

typedef unsigned short u16;
typedef unsigned int u32;
typedef __bf16 bf16x8 __attribute__((ext_vector_type(8)));
typedef float f32x4 __attribute__((ext_vector_type(4)));

#define T_TOK 4096
#define HID   1024
#define INTER 4096
#define NEXP  8

// ---------------- workspace layout (bytes) ----------------
#define WS_NEEDED 209978368ull

__device__ __forceinline__ u16 f2bf(float f) {
    u32 u = __builtin_bit_cast(u32, f);
    u += 0x7FFFu + ((u >> 16) & 1u);   // round-to-nearest-even
    return (u16)(u >> 16);
}

__device__ __forceinline__ void gl2lds16(const void* g, void* l) {
    __builtin_amdgcn_global_load_lds(
        (const __attribute__((address_space(1))) u32*)g,
        (__attribute__((address_space(3))) u32*)l, 16, 0, 0);
}

// fast exact-enough gelu: tanh approximation, stable rational form.
// gelu(v) = 0.5 v (1+tanh(u)) = v / (1 + exp(-2u)), u = 0.79788456(v + 0.044715 v^3)
__device__ __forceinline__ float fast_gelu(float v) {
    float u2 = v * (-1.5957691216f - 0.0713548163f * v * v);  // -2u
    return v / (1.0f + __expf(u2));
}

// ---------------- router: fp32 logits + top-2 lists ----------------
__global__ __launch_bounds__(256) void router_kernel(
    const float* __restrict__ x, const float* __restrict__ gw,
    float* __restrict__ logits, int* __restrict__ counts,
    int* __restrict__ tlist, float* __restrict__ wlist)
{
    const int lane = threadIdx.x & 63, wv = threadIdx.x >> 6;
    const int t = blockIdx.x * 4 + wv;
    const float* xr = x + (size_t)t * HID;
    float a[8] = {0.f,0.f,0.f,0.f,0.f,0.f,0.f,0.f};
    for (int h = lane; h < HID; h += 64) {
        float xv = xr[h];
        const float4* g4 = (const float4*)(gw + h * 8);
        float4 g0 = g4[0], g1 = g4[1];
        a[0] += xv * g0.x; a[1] += xv * g0.y; a[2] += xv * g0.z; a[3] += xv * g0.w;
        a[4] += xv * g1.x; a[5] += xv * g1.y; a[6] += xv * g1.z; a[7] += xv * g1.w;
    }
#pragma unroll
    for (int e = 0; e < 8; e++) {
        float v = a[e];
        for (int o = 32; o > 0; o >>= 1) v += __shfl_down(v, o, 64);
        a[e] = v;
    }
    if (lane == 0) {
#pragma unroll
        for (int e = 0; e < 8; e++) logits[(size_t)t * 8 + e] = a[e];
        int e1 = 0; float b1 = a[0];
        for (int e = 1; e < 8; e++) if (a[e] > b1) { b1 = a[e]; e1 = e; }
        int e2 = -1; float b2 = -1e30f;
        for (int e = 0; e < 8; e++) if (e != e1 && a[e] > b2) { b2 = a[e]; e2 = e; }
        // softmax->top2->renorm == 2-way softmax over (b1,b2)
        float wa = 1.0f / (1.0f + expf(b2 - b1));
        float wb = 1.0f - wa;
        int p = atomicAdd(&counts[e1], 1);
        tlist[e1 * T_TOK + p] = t; wlist[e1 * T_TOK + p] = wa;
        p = atomicAdd(&counts[e2], 1);
        tlist[e2 * T_TOK + p] = t; wlist[e2 * T_TOK + p] = wb;
    }
}

__global__ void scan_kernel(const int* __restrict__ counts, int* __restrict__ offs)
{
    if (threadIdx.x == 0) {
        int s = 0;
        for (int e = 0; e < 8; e++) { offs[e] = s; s += counts[e]; }
    }
}

// ---------------- fp32 -> bf16 convert (x) ----------------
__global__ __launch_bounds__(256) void convert_x_kernel(
    const float* __restrict__ src, u16* __restrict__ dst)
{
    const int idx = (blockIdx.x * 256 + threadIdx.x) * 8;
    float4 f0 = *(const float4*)(src + idx);
    float4 f1 = *(const float4*)(src + idx + 4);
    uint4 o;
    o.x = (u32)f2bf(f0.x) | ((u32)f2bf(f0.y) << 16);
    o.y = (u32)f2bf(f0.z) | ((u32)f2bf(f0.w) << 16);
    o.z = (u32)f2bf(f1.x) | ((u32)f2bf(f1.y) << 16);
    o.w = (u32)f2bf(f1.z) | ((u32)f2bf(f1.w) << 16);
    *(uint4*)(dst + idx) = o;
}

// ------- transpose + convert v2: src[E][R][C] f32 -> dst[E][C][R] bf16 -------
// float4 reads (16B/lane), LDS transposed scatter (2-way aliasing = free),
// uint4 stores (16B/lane, 128B contiguous per 8 lanes).
__global__ __launch_bounds__(256) void transpose_convert_kernel(
    const float* __restrict__ src, u16* __restrict__ dst, int R, int C)
{
    __shared__ float tl[64][65];   // [c][r], +1 pad
    const int e = blockIdx.z;
    const int c0 = blockIdx.x * 64, r0 = blockIdx.y * 64;
    const float* s = src + (size_t)e * R * C + (size_t)r0 * C + c0;
    const int tid = threadIdx.x;
#pragma unroll
    for (int it = 0; it < 4; it++) {
        int idx = it * 256 + tid;       // 0..1023
        int r = idx >> 4;               // 0..63
        int c4 = (idx & 15) * 4;        // 0,4,...,60
        float4 v = *(const float4*)(s + (size_t)r * C + c4);
        tl[c4 + 0][r] = v.x;
        tl[c4 + 1][r] = v.y;
        tl[c4 + 2][r] = v.z;
        tl[c4 + 3][r] = v.w;
    }
    __syncthreads();
    u16* d = dst + (size_t)e * C * R + (size_t)c0 * R + r0;
#pragma unroll
    for (int it = 0; it < 2; it++) {
        int idx = it * 256 + tid;       // 0..511
        int c = idx >> 3;               // 0..63
        int rg = (idx & 7) * 8;         // 0,8,...,56
        u32 o[4];
#pragma unroll
        for (int p = 0; p < 4; p++)
            o[p] = (u32)f2bf(tl[c][rg + 2 * p]) | ((u32)f2bf(tl[c][rg + 2 * p + 1]) << 16);
        *(uint4*)(d + (size_t)c * R + rg) = *(uint4*)o;
    }
}

// ---------------- GEMM1: h1 = gelu(x_gathered @ w1), bf16 MFMA ----------------
__global__ __launch_bounds__(256, 1) void gemm1_kernel(
    const u16* __restrict__ xb, const u16* __restrict__ w1t,
    const int* __restrict__ counts, const int* __restrict__ offs,
    const int* __restrict__ tlist, u16* __restrict__ h1b)
{
    const int e = blockIdx.z, mt = blockIdx.y, nt = blockIdx.x;
    const int cnt = counts[e];
    if (mt * 128 >= cnt) return;
    __shared__ __align__(16) u16 As[8192];   // [m 0..127][k-chunk swizzled]
    __shared__ __align__(16) u16 Bs[8192];   // [n 0..127][k-chunk swizzled]
    __shared__ int toks[128];
    const int tid = threadIdx.x, lane = tid & 63, wv = tid >> 6;
    if (tid < 128) toks[tid] = tlist[e * T_TOK + min(mt * 128 + tid, cnt - 1)];
    __syncthreads();

    f32x4 acc[4][4] = {};
    const int wm = wv & 1, wn = wv >> 1;
    const int sj = tid >> 3, sp = tid & 7;

    size_t abase[4], bbase[4];
    const u16* w1base = w1t + ((size_t)e * INTER + (size_t)nt * 128) * HID;
#pragma unroll
    for (int j = 0; j < 4; j++) {
        int m = j * 32 + sj;
        abase[j] = (size_t)toks[m] * HID + ((sp - m) & 7) * 8;
        bbase[j] = (size_t)m * HID + ((sp - m) & 7) * 8;
    }

    for (int h0 = 0; h0 < HID; h0 += 64) {
#pragma unroll
        for (int j = 0; j < 4; j++)
            gl2lds16(xb + abase[j] + h0, &As[j * 2048 + wv * 512]);
#pragma unroll
        for (int j = 0; j < 4; j++)
            gl2lds16(w1base + bbase[j] + h0, &Bs[j * 2048 + wv * 512]);
        __syncthreads();
#pragma unroll
        for (int kk = 0; kk < 2; kk++) {
            bf16x8 a[4], b[4];
            const int jjb = kk * 4 + (lane >> 4);
#pragma unroll
            for (int i = 0; i < 4; i++) {
                int m = wm * 64 + i * 16 + (lane & 15);
                a[i] = *(const bf16x8*)&As[m * 64 + ((jjb + m) & 7) * 8];
            }
#pragma unroll
            for (int i = 0; i < 4; i++) {
                int n = wn * 64 + i * 16 + (lane & 15);
                b[i] = *(const bf16x8*)&Bs[n * 64 + ((jjb + n) & 7) * 8];
            }
#pragma unroll
            for (int i = 0; i < 4; i++)
#pragma unroll
                for (int j = 0; j < 4; j++)
                    acc[i][j] = __builtin_amdgcn_mfma_f32_16x16x32_bf16(
                        a[i], b[j], acc[i][j], 0, 0, 0);
        }
        __syncthreads();
    }

    const int pb = offs[e] + mt * 128;
    const bool full = (mt * 128 + 128 <= cnt);
#pragma unroll
    for (int i = 0; i < 4; i++) {
        const int mb = wm * 64 + i * 16 + ((lane >> 4) << 2);
#pragma unroll
        for (int j = 0; j < 4; j++) {
            const int n = nt * 128 + wn * 64 + j * 16 + (lane & 15);
#pragma unroll
            for (int r = 0; r < 4; r++) {
                const int m = mb + r;
                if (full || mt * 128 + m < cnt) {
                    h1b[(size_t)(pb + m) * INTER + n] = f2bf(fast_gelu(acc[i][j][r]));
                }
            }
        }
    }
}

// -------- GEMM2: out += weight * (h1 @ w2), bf16 MFMA, split-K=2, atomics -----
__global__ __launch_bounds__(256, 1) void gemm2_kernel(
    const u16* __restrict__ h1b, const u16* __restrict__ w2t,
    const int* __restrict__ counts, const int* __restrict__ offs,
    const int* __restrict__ tlist, const float* __restrict__ wlist,
    float* __restrict__ out)
{
    const int e = blockIdx.z, mt = blockIdx.y;
    const int nt = blockIdx.x & 7, ks = blockIdx.x >> 3;
    const int cnt = counts[e];
    if (mt * 128 >= cnt) return;
    __shared__ __align__(16) u16 As[8192];
    __shared__ __align__(16) u16 Bs[8192];
    __shared__ int toks[128];
    __shared__ float wgt[128];
    const int tid = threadIdx.x, lane = tid & 63, wv = tid >> 6;
    if (tid < 128) {
        int gi = e * T_TOK + min(mt * 128 + tid, cnt - 1);
        toks[tid] = tlist[gi];
        wgt[tid] = wlist[gi];
    }
    __syncthreads();

    f32x4 acc[4][4] = {};
    const int wm = wv & 1, wn = wv >> 1;
    const int sj = tid >> 3, sp = tid & 7;

    size_t abase[4], bbase[4];
    const u16* w2base = w2t + ((size_t)e * HID + (size_t)nt * 128) * INTER;
    const int prow = offs[e];
#pragma unroll
    for (int j = 0; j < 4; j++) {
        int m = j * 32 + sj;
        int row = prow + min(mt * 128 + m, cnt - 1);
        abase[j] = (size_t)row * INTER + ((sp - m) & 7) * 8;
        bbase[j] = (size_t)m * INTER + ((sp - m) & 7) * 8;
    }

    const int i_lo = ks * (INTER / 2), i_hi = i_lo + (INTER / 2);
    for (int i0 = i_lo; i0 < i_hi; i0 += 64) {
#pragma unroll
        for (int j = 0; j < 4; j++)
            gl2lds16(h1b + abase[j] + i0, &As[j * 2048 + wv * 512]);
#pragma unroll
        for (int j = 0; j < 4; j++)
            gl2lds16(w2base + bbase[j] + i0, &Bs[j * 2048 + wv * 512]);
        __syncthreads();
#pragma unroll
        for (int kk = 0; kk < 2; kk++) {
            bf16x8 a[4], b[4];
            const int jjb = kk * 4 + (lane >> 4);
#pragma unroll
            for (int i = 0; i < 4; i++) {
                int m = wm * 64 + i * 16 + (lane & 15);
                a[i] = *(const bf16x8*)&As[m * 64 + ((jjb + m) & 7) * 8];
            }
#pragma unroll
            for (int i = 0; i < 4; i++) {
                int n = wn * 64 + i * 16 + (lane & 15);
                b[i] = *(const bf16x8*)&Bs[n * 64 + ((jjb + n) & 7) * 8];
            }
#pragma unroll
            for (int i = 0; i < 4; i++)
#pragma unroll
                for (int j = 0; j < 4; j++)
                    acc[i][j] = __builtin_amdgcn_mfma_f32_16x16x32_bf16(
                        a[i], b[j], acc[i][j], 0, 0, 0);
        }
        __syncthreads();
    }

    const bool full = (mt * 128 + 128 <= cnt);
#pragma unroll
    for (int i = 0; i < 4; i++) {
        const int mb = wm * 64 + i * 16 + ((lane >> 4) << 2);
#pragma unroll
        for (int j = 0; j < 4; j++) {
            const int n = nt * 128 + wn * 64 + j * 16 + (lane & 15);
#pragma unroll
            for (int r = 0; r < 4; r++) {
                const int m = mb + r;
                if (full || mt * 128 + m < cnt) {
                    atomicAdd(&out[(size_t)toks[m] * HID + n], acc[i][j][r] * wgt[m]);
                }
            }
        }
    }
}

extern "C" void kernel_launch(void* const* d_in, const int* in_sizes, int n_in,
                              void* d_out, int out_size, void* d_ws, size_t ws_size,
                              hipStream_t stream)
{
    const float* x  = (const float*)d_in[0];   // [4,1024,1024]
    const float* gw = (const float*)d_in[1];   // [1024,8]
    const float* w1 = (const float*)d_in[2];   // [8,1024,4096]
    const float* w2 = (const float*)d_in[3];   // [8,4096,1024]
    float* out    = (float*)d_out;             // 4194304 out + 32768 logits
    float* logits = out + 4194304;

    char* ws = (char*)d_ws;
    int*   counts = (int*)ws;
    int*   offs   = (int*)(ws + 256);
    int*   tlist  = (int*)(ws + 1024);
    float* wlist  = (float*)(ws + 132096);
    u16*   xb     = (u16*)(ws + 263168);
    u16*   w1t    = (u16*)(ws + 8651776);
    u16*   w2t    = (u16*)(ws + 75760640);
    u16*   h1b    = (u16*)(ws + 142869504);

    if (ws_size < WS_NEEDED) return;

    hipMemsetAsync(out, 0, 4194304 * sizeof(float), stream);
    hipMemsetAsync(counts, 0, 256, stream);

    router_kernel<<<1024, 256, 0, stream>>>(x, gw, logits, counts, tlist, wlist);
    scan_kernel<<<1, 64, 0, stream>>>(counts, offs);
    convert_x_kernel<<<2048, 256, 0, stream>>>(x, xb);
    // w1 [E][H=1024][I=4096] -> w1t [E][I][H]
    transpose_convert_kernel<<<dim3(64, 16, 8), 256, 0, stream>>>(w1, w1t, HID, INTER);
    // w2 [E][I=4096][H=1024] -> w2t [E][H][I]
    transpose_convert_kernel<<<dim3(16, 64, 8), 256, 0, stream>>>(w2, w2t, INTER, HID);

    // gemm1: grid x=nt(32), y=mt(16), z=e(8)
    gemm1_kernel<<<dim3(32, 16, 8), 256, 0, stream>>>(xb, w1t, counts, offs, tlist, h1b);
    // gemm2: grid x = nt(8) + 8*ks(2), y=mt(16), z=e(8)
    gemm2_kernel<<<dim3(16, 16, 8), 256, 0, stream>>>(h1b, w2t, counts, offs, tlist, wlist, out);
}